// Round 7
// baseline (28.219 us; speedup 1.0000x reference)
//
#include <hip/hip_runtime.h>

// ---------------- problem constants ----------------
#define DTSTEP  3600.0
#define T_STEPS 1048576
#define LCH     8                     // u-rows per chunk (one chunk per thread)
#define TPB     512                   // threads per block
#define NBLK    256                   // block = 4096 steps; 256 blocks = 256 CUs (co-resident)
#define MAGIC   0x51CAFE17u

// sPW[k-3] = M^(2^k) as f32, k=3..19 (17 matrices):
//   base 0, r=0..8 : M^(8*2^r)    -> intra-block (bits of tid, chunk = 8 steps)
//   base 9, r=0..7 : M^(4096*2^r) -> cross-block (bits of block distance)
// ws: aggregates float[256*3] at 0; flags uint[256] at float-offset 1024.

__device__ inline void matsq3(double* C){
  double R[9];
#pragma unroll
  for (int r=0;r<3;r++){
#pragma unroll
    for (int c=0;c<3;c++){
      R[r*3+c] = C[r*3+0]*C[0+c] + C[r*3+1]*C[3+c] + C[r*3+2]*C[6+c];
    }
  }
#pragma unroll
  for (int k=0;k<9;k++) C[k]=R[k];
}

// thread-0-per-block: build M,N (f32) + 17 matrix powers via f64 squaring
__device__ void setup_from_rc(const float* __restrict__ rc,
                              float* __restrict__ sMN, float* __restrict__ sPW){
  const float Rg = rc[0]*10.f+1.f, Ri = rc[1]*10.f+1.f, Re = rc[2]*10.f+1.f, Rw = rc[3]*10.f+1.f;
  const float Cai = rc[4]*1e6f+1e5f, Cwe = rc[5]*1e6f+1e5f, Cwi = rc[6]*1e6f+1e5f;
  double Md[9];
  Md[0] = 1.0 + DTSTEP*(-(1.0/Rg + 1.0/Ri)/Cai);
  Md[1] = 0.0;
  Md[2] = DTSTEP*(1.0/((double)Ri*(double)Cai));
  Md[3] = 0.0;
  Md[4] = 1.0 + DTSTEP*(-(1.0/Re + 1.0/Rw)/Cwe);
  Md[5] = DTSTEP*(1.0/((double)Rw*(double)Cwe));
  Md[6] = DTSTEP*(1.0/((double)Ri*(double)Cwi));
  Md[7] = DTSTEP*(1.0/((double)Rw*(double)Cwi));
  Md[8] = 1.0 + DTSTEP*(-(1.0/Rw + 1.0/Ri)/Cwi);
  sMN[0]=(float)Md[0]; sMN[1]=(float)Md[2]; sMN[2]=(float)Md[4]; sMN[3]=(float)Md[5];
  sMN[4]=(float)Md[6]; sMN[5]=(float)Md[7]; sMN[6]=(float)Md[8];
  sMN[7] =(float)(DTSTEP*(1.0/((double)Rg*(double)Cai)));   // N0
  sMN[8] =(float)(DTSTEP*(1.0/(double)Cai));                // N1
  sMN[9] =(float)(DTSTEP*(1.0/(double)Cai));                // N2
  sMN[10]=(float)(DTSTEP*(1.0/((double)Re*(double)Cwe)));   // N5
  sMN[11]=(float)(DTSTEP*(1.0/(double)Cwe));                // N8
  sMN[12]=(float)(DTSTEP*(1.0/(double)Cwi));                // N14
  double C[9];
#pragma unroll
  for (int k=0;k<9;k++) C[k]=Md[k];
  for (int k=1;k<=19;k++){
    matsq3(C);                                   // C = M^(2^k)
    if (k>=3){
#pragma unroll
      for (int j=0;j<9;j++) sPW[(k-3)*9+j] = (float)C[j];
    }
  }
}

struct MN { float M0,M2,M4,M5,M6,M7,M8, N0,N1,N2,N5,N8,N14; };

__device__ inline MN mn_from_lds(const float* __restrict__ sMN){
  MN p;
  p.M0=sMN[0]; p.M2=sMN[1]; p.M4=sMN[2]; p.M5=sMN[3];
  p.M6=sMN[4]; p.M7=sMN[5]; p.M8=sMN[6];
  p.N0=sMN[7]; p.N1=sMN[8]; p.N2=sMN[9];
  p.N5=sMN[10]; p.N8=sMN[11]; p.N14=sMN[12];
  return p;
}

// v <- M v + N u_j over the chunk (exploits exact zeros in M,N)
__device__ inline void chunk_v(const float* uu, const MN& mn, float& v0, float& v1, float& v2){
  v0=0.f; v1=0.f; v2=0.f;
#pragma unroll
  for (int j=0;j<LCH;j++){
    const float u0=uu[j*5+0],u1=uu[j*5+1],u2=uu[j*5+2],u3=uu[j*5+3],u4v=uu[j*5+4];
    const float c0 = fmaf(mn.N0,u0, fmaf(mn.N1,u1, mn.N2*u2));
    const float c1 = fmaf(mn.N5,u0, mn.N8*u3);
    const float c2 = mn.N14*u4v;
    const float n0 = fmaf(mn.M0,v0, fmaf(mn.M2,v2, c0));
    const float n1 = fmaf(mn.M4,v1, fmaf(mn.M5,v2, c1));
    const float n2 = fmaf(mn.M6,v0, fmaf(mn.M7,v1, fmaf(mn.M8,v2, c2)));
    v0=n0; v1=n1; v2=n2;
  }
}

// x <- M^(step*e) x via bit-decomposed vector applies (powers of M commute)
__device__ inline void apply_pow(const float* __restrict__ sPW, int base, unsigned e,
                                 float& x0, float& x1, float& x2){
#pragma unroll
  for (int r=0;r<9;r++){
    if (e & (1u<<r)){
      const float* Q = &sPW[(base+r)*9];
      const float y0 = fmaf(Q[0],x0, fmaf(Q[1],x1, Q[2]*x2));
      const float y1 = fmaf(Q[3],x0, fmaf(Q[4],x1, Q[5]*x2));
      const float y2 = fmaf(Q[6],x0, fmaf(Q[7],x1, Q[8]*x2));
      x0=y0; x1=y1; x2=y2;
    }
  }
}

__global__ __launch_bounds__(TPB, 2) void k_fused(const float* __restrict__ u,
                                                  const float* __restrict__ rc,
                                                  const float* __restrict__ x_init,
                                                  float* __restrict__ wsAgg,
                                                  unsigned int* __restrict__ wsFlag,
                                                  float* __restrict__ out){
  __shared__ float sMN[13];
  __shared__ float sPW[17*9];
  __shared__ float buf[2][TPB*3];
  __shared__ float partial[8][3];
  __shared__ float sS[3];
  const int tid = threadIdx.x;
  const int blk = blockIdx.x;
  const int i   = blk*TPB + tid;                 // chunk id
  // u loads issued first (in flight under setup)
  float uu[LCH*5];
  const float4* u4 = reinterpret_cast<const float4*>(u) + (size_t)i*(LCH*5/4);
#pragma unroll
  for (int k=0;k<LCH*5/4;k++){
    const float4 q = u4[k];
    uu[k*4+0]=q.x; uu[k*4+1]=q.y; uu[k*4+2]=q.z; uu[k*4+3]=q.w;
  }
  if (tid==0) setup_from_rc(rc, sMN, sPW);
  __syncthreads();
  const MN mn = mn_from_lds(sMN);
  float t0,t1,t2;
  chunk_v(uu, mn, t0,t1,t2);
  // ---- 512-wide inclusive affine scan of pure-v (no block start folded) ----
  buf[0][tid*3+0]=t0; buf[0][tid*3+1]=t1; buf[0][tid*3+2]=t2;
  __syncthreads();
  int cur=0;
#pragma unroll
  for (int r=0;r<9;r++){
    const int d = 1<<r;
    const float Q0=sPW[r*9+0],Q1=sPW[r*9+1],Q2=sPW[r*9+2],
                Q3=sPW[r*9+3],Q4=sPW[r*9+4],Q5=sPW[r*9+5],
                Q6=sPW[r*9+6],Q7=sPW[r*9+7],Q8=sPW[r*9+8];
    float p0=0.f,p1=0.f,p2=0.f;
    if (tid >= d){
      const int s=(tid-d)*3;
      p0=buf[cur][s+0]; p1=buf[cur][s+1]; p2=buf[cur][s+2];
    }
    t0 = fmaf(Q0,p0, fmaf(Q1,p1, fmaf(Q2,p2, t0)));
    t1 = fmaf(Q3,p0, fmaf(Q4,p1, fmaf(Q5,p2, t1)));
    t2 = fmaf(Q6,p0, fmaf(Q7,p1, fmaf(Q8,p2, t2)));
    buf[cur^1][tid*3+0]=t0; buf[cur^1][tid*3+1]=t1; buf[cur^1][tid*3+2]=t2;
    __syncthreads();
    cur ^= 1;
  }
  // ---- publish block aggregate (inclusive value of last thread) ----
  if (tid==TPB-1){
    __hip_atomic_store(&wsAgg[blk*3+0], t0, __ATOMIC_RELAXED, __HIP_MEMORY_SCOPE_AGENT);
    __hip_atomic_store(&wsAgg[blk*3+1], t1, __ATOMIC_RELAXED, __HIP_MEMORY_SCOPE_AGENT);
    __hip_atomic_store(&wsAgg[blk*3+2], t2, __ATOMIC_RELAXED, __HIP_MEMORY_SCOPE_AGENT);
    __hip_atomic_store(&wsFlag[blk], MAGIC, __ATOMIC_RELEASE, __HIP_MEMORY_SCOPE_AGENT);
  }
  // ---- block start S = M^(4096*blk) x_init + sum_{j<blk} M^(4096*(blk-1-j)) v_j ----
  float c0=0.f, c1=0.f, c2=0.f;
  if (tid < blk){                                // predecessors' aggregates
    while (__hip_atomic_load(&wsFlag[tid], __ATOMIC_ACQUIRE, __HIP_MEMORY_SCOPE_AGENT) != MAGIC){}
    c0=__hip_atomic_load(&wsAgg[tid*3+0], __ATOMIC_RELAXED, __HIP_MEMORY_SCOPE_AGENT);
    c1=__hip_atomic_load(&wsAgg[tid*3+1], __ATOMIC_RELAXED, __HIP_MEMORY_SCOPE_AGENT);
    c2=__hip_atomic_load(&wsAgg[tid*3+2], __ATOMIC_RELAXED, __HIP_MEMORY_SCOPE_AGENT);
    apply_pow(sPW, 9, (unsigned)(blk-1-tid), c0,c1,c2);
  } else if (tid==TPB-1){                        // x_init term
    c0=x_init[0]; c1=x_init[1]; c2=x_init[2];
    apply_pow(sPW, 9, (unsigned)blk, c0,c1,c2);
  }
  // sum the 3-vectors across the block: wave shfl tree + 8 partials
#pragma unroll
  for (int off=32; off>0; off>>=1){
    c0 += __shfl_down(c0, off, 64);
    c1 += __shfl_down(c1, off, 64);
    c2 += __shfl_down(c2, off, 64);
  }
  if ((tid & 63)==0){
    partial[tid>>6][0]=c0; partial[tid>>6][1]=c1; partial[tid>>6][2]=c2;
  }
  __syncthreads();
  if (tid==0){
    float S0=0.f,S1=0.f,S2=0.f;
#pragma unroll
    for (int w=0;w<8;w++){ S0+=partial[w][0]; S1+=partial[w][1]; S2+=partial[w][2]; }
    sS[0]=S0; sS[1]=S1; sS[2]=S2;
  }
  __syncthreads();
  // ---- chunk start: x = M^(8*tid) S + t_prev  (pure VALU, no second scan) ----
  float x0=sS[0], x1=sS[1], x2=sS[2];
  apply_pow(sPW, 0, (unsigned)tid, x0,x1,x2);
  if (tid>0){
    const int s=(tid-1)*3;
    x0 += buf[cur][s+0]; x1 += buf[cur][s+1]; x2 += buf[cur][s+2];
  }
  // ---- replay 8 steps, write f32 outputs ----
  float px[LCH*3], py[LCH];
#pragma unroll
  for (int j=0;j<LCH;j++){
    py[j]=x0;                                    // y_t = C x_t (pre-update)
    const float u0=uu[j*5+0],u1=uu[j*5+1],u2=uu[j*5+2],u3=uu[j*5+3],u4v=uu[j*5+4];
    const float c0v = fmaf(mn.N0,u0, fmaf(mn.N1,u1, mn.N2*u2));
    const float c1v = fmaf(mn.N5,u0, mn.N8*u3);
    const float c2v = mn.N14*u4v;
    const float n0 = fmaf(mn.M0,x0, fmaf(mn.M2,x2, c0v));
    const float n1 = fmaf(mn.M4,x1, fmaf(mn.M5,x2, c1v));
    const float n2 = fmaf(mn.M6,x0, fmaf(mn.M7,x1, fmaf(mn.M8,x2, c2v)));
    x0=n0; x1=n1; x2=n2;
    px[j*3+0]=x0; px[j*3+1]=x1; px[j*3+2]=x2;    // xsol_t = x_{t+1}
  }
  float4* xo4 = reinterpret_cast<float4*>(out) + (size_t)i*6;
#pragma unroll
  for (int m=0;m<6;m++)
    xo4[m] = make_float4(px[4*m+0],px[4*m+1],px[4*m+2],px[4*m+3]);
  float4* yo4 = reinterpret_cast<float4*>(out) + (size_t)(3*T_STEPS/4) + (size_t)i*2;
  yo4[0] = make_float4(py[0],py[1],py[2],py[3]);
  yo4[1] = make_float4(py[4],py[5],py[6],py[7]);
}

extern "C" void kernel_launch(void* const* d_in, const int* in_sizes, int n_in,
                              void* d_out, int out_size, void* d_ws, size_t ws_size,
                              hipStream_t stream) {
  (void)out_size; (void)ws_size;
  const float* x_init = (const float*)d_in[0];
  const float* u      = (const float*)d_in[1];
  const float* rc     = (const float*)d_in[2];
  for (int k=0;k<n_in;k++){
    if (in_sizes[k]==3) x_init = (const float*)d_in[k];
    else if (in_sizes[k]==7) rc = (const float*)d_in[k];
    else if (in_sizes[k]==T_STEPS*5) u = (const float*)d_in[k];
  }
  float* wsAgg = (float*)d_ws;                         // 256*3 floats
  unsigned int* wsFlag = (unsigned int*)((float*)d_ws + 1024);  // 256 flags
  float* out = (float*)d_out;

  k_fused<<<NBLK, TPB, 0, stream>>>(u, rc, x_init, wsAgg, wsFlag, out);
}